// Round 16
// baseline (332.360 us; speedup 1.0000x reference)
//
#include <hip/hip_runtime.h>
#include <hip/hip_bf16.h>

typedef __attribute__((ext_vector_type(8))) short bf16x8;
typedef __attribute__((ext_vector_type(4))) float f32x4;
typedef unsigned short u16;

#define T_TOK 2048
#define HID 4096
#define NH 32
#define NKV 8
#define HD 128
#define QKVN 6144   // (NH + 2*NKV) * HD
#define KOFF 4096   // k column offset in qkv
#define VOFF 5120   // v column offset in qkv
#define ATTN_SCALE 0.08838834764831845f

static __device__ __forceinline__ float bf2f(u16 x) {
    union { float f; unsigned u; } v; v.u = ((unsigned)x) << 16; return v.f;
}
static __device__ __forceinline__ u16 f2bf(float f) {
    union { float f; unsigned u; } v; v.f = f;
    unsigned u = v.u;
    unsigned r = (u + 0x7fff + ((u >> 16) & 1)) >> 16;
    return (u16)r;
}

// async global->LDS, 16B per lane; LDS dest = WAVE-UNIFORM base (HW adds lane*16B)
static __device__ __forceinline__ void gload16(const u16* g, u16* l) {
    __builtin_amdgcn_global_load_lds((const __attribute__((address_space(1))) void*)g,
                                     (__attribute__((address_space(3))) void*)l, 16, 0, 0);
}

#define VMC(n) asm volatile("s_waitcnt vmcnt(%0)" :: "i"(n) : "memory")
#define LGKM0() asm volatile("s_waitcnt lgkmcnt(0)" ::: "memory")
#define BAR() __builtin_amdgcn_s_barrier()
#define SCHB() __builtin_amdgcn_sched_barrier(0)

// ---------------- elementwise f32 -> bf16 ----------------
__global__ __launch_bounds__(256) void convk(const float* __restrict__ in, u16* __restrict__ out) {
    int i = blockIdx.x * 256 + threadIdx.x;
    float4 v = ((const float4*)in)[i];
    ushort4 o;
    o.x = f2bf(v.x); o.y = f2bf(v.y); o.z = f2bf(v.z); o.w = f2bf(v.w);
    ((ushort4*)out)[i] = o;
}

// ---------------- transpose + convert: in f32 [R][C] -> out bf16 [C][R] ----------------
__global__ __launch_bounds__(256) void transpk(const float* __restrict__ in, u16* __restrict__ out,
                                               int R, int C) {
    __shared__ float tile[64][65];
    int c0 = blockIdx.x * 64, r0 = blockIdx.y * 64;
    int tid = threadIdx.x;
#pragma unroll
    for (int it = 0; it < 4; ++it) {
        int ci = it * 256 + tid;
        int r = ci >> 4, c4 = (ci & 15) * 4;
        float4 v = *(const float4*)&in[(size_t)(r0 + r) * C + c0 + c4];
        tile[r][c4 + 0] = v.x; tile[r][c4 + 1] = v.y; tile[r][c4 + 2] = v.z; tile[r][c4 + 3] = v.w;
    }
    __syncthreads();
#pragma unroll
    for (int it = 0; it < 4; ++it) {
        int ci = it * 256 + tid;
        int c = ci >> 4, rq = (ci & 15) * 4;
        ushort4 o;
        o.x = f2bf(tile[rq + 0][c]); o.y = f2bf(tile[rq + 1][c]);
        o.z = f2bf(tile[rq + 2][c]); o.w = f2bf(tile[rq + 3][c]);
        *(ushort4*)&out[(size_t)(c0 + c) * R + r0 + rq] = o;
    }
}

// ------- pipelined GEMM (R14 best): BM=256 BK=32, depth-3, counted vmcnt, waves 4M x 2N -------
// XCD-cluster mapping: XCD j owns an 8m x 4n cluster (per-K-step miss 176KB).
template <int BN, int OUTF32>
__global__ __launch_bounds__(512) void gemm8p(const u16* __restrict__ A, const u16* __restrict__ Bt,
                                              void* __restrict__ Cout, int M, int N, int K) {
    constexpr int BM = 256, BK = 32;
    constexpr int WN = BN / 2;
    constexpr int NF = WN / 16;
    constexpr int BCH = BN / 16;
    constexpr int CA = 2 + (BCH + 7) / 8;
    constexpr int CB = 2 + BCH / 8;
    constexpr int ABUF = BM * BK;
    constexpr int BBUF = BN * BK;
    constexpr int BUFSZ = ABUF + BBUF;

    __shared__ __attribute__((aligned(16))) u16 lds[4 * BUFSZ];

    int bid = blockIdx.x;
    int m0 = ((bid >> 3) & 7) * BM;
    int n0 = ((bid & 7) * 4 + (bid >> 6)) * BN;
    int tid = threadIdx.x, lane = tid & 63, wid = tid >> 6;
    int wm = wid >> 1, wn = wid & 1;
    int l15 = lane & 15, g4 = lane >> 4;
    int srow = lane >> 2;
    int sslot = (lane & 3) ^ ((lane >> 3) & 3);
    int swz = (g4 ^ ((l15 >> 1) & 3)) * 8;
    int NK = K / BK;
    bool shortw = (CA != CB) && (wid >= 4);

    auto STAGE = [&](int kt, int c) {
        u16* base = &lds[(kt & 3) * BUFSZ];
        size_t kcol = (size_t)kt * BK + sslot * 8;
        if (c < 2) {
            int ch = wid * 2 + c;
            gload16(&A[(size_t)(m0 + ch * 16 + srow) * K + kcol], base + ch * 512);
        } else {
            int ch = (c - 2) * 8 + wid;
            if (ch < BCH)
                gload16(&Bt[(size_t)(n0 + ch * 16 + srow) * K + kcol], base + ABUF + ch * 512);
        }
    };

    f32x4 acc[4][NF];
#pragma unroll
    for (int i = 0; i < 4; ++i)
#pragma unroll
        for (int j = 0; j < NF; ++j) acc[i][j] = (f32x4){0.f, 0.f, 0.f, 0.f};

    for (int t = 0; t < 3; ++t)
        for (int c = 0; c < CA; ++c) STAGE(t, c);
    if (shortw) VMC(2 * CB); else VMC(2 * CA);
    BAR(); SCHB();

    for (int g = 0; g < NK; ++g) {
        const u16* ab = &lds[(g & 3) * BUFSZ];
        const u16* bb = ab + ABUF;

        bf16x8 bfr[NF], af0, af1;
#pragma unroll
        for (int j = 0; j < NF; ++j)
            bfr[j] = *(const bf16x8*)&bb[(wn * WN + j * 16 + l15) * BK + swz];
        af0 = *(const bf16x8*)&ab[(wm * 64 + 0 * 16 + l15) * BK + swz];
        af1 = *(const bf16x8*)&ab[(wm * 64 + 1 * 16 + l15) * BK + swz];
        if (g + 3 < NK) {
            STAGE(g + 3, 0); STAGE(g + 3, 1);
        }
        __builtin_amdgcn_s_setprio(1);
#pragma unroll
        for (int j = 0; j < NF; ++j) {
            acc[0][j] = __builtin_amdgcn_mfma_f32_16x16x32_bf16(af0, bfr[j], acc[0][j], 0, 0, 0);
            acc[1][j] = __builtin_amdgcn_mfma_f32_16x16x32_bf16(af1, bfr[j], acc[1][j], 0, 0, 0);
        }
        __builtin_amdgcn_s_setprio(0);

        bf16x8 af2, af3;
        af2 = *(const bf16x8*)&ab[(wm * 64 + 2 * 16 + l15) * BK + swz];
        af3 = *(const bf16x8*)&ab[(wm * 64 + 3 * 16 + l15) * BK + swz];
        if (g + 3 < NK) {
#pragma unroll
            for (int c = 2; c < CA; ++c) STAGE(g + 3, c);
        }
        __builtin_amdgcn_s_setprio(1);
#pragma unroll
        for (int j = 0; j < NF; ++j) {
            acc[2][j] = __builtin_amdgcn_mfma_f32_16x16x32_bf16(af2, bfr[j], acc[2][j], 0, 0, 0);
            acc[3][j] = __builtin_amdgcn_mfma_f32_16x16x32_bf16(af3, bfr[j], acc[3][j], 0, 0, 0);
        }
        __builtin_amdgcn_s_setprio(0);

        if (g < NK - 3)       { if (shortw) VMC(2 * CB); else VMC(2 * CA); }
        else if (g == NK - 3) { if (shortw) VMC(CB);     else VMC(CA); }
        else if (g == NK - 2) VMC(0);
        BAR(); SCHB();
    }

#pragma unroll
    for (int mi = 0; mi < 4; ++mi)
#pragma unroll
        for (int j = 0; j < NF; ++j)
#pragma unroll
            for (int i = 0; i < 4; ++i) {
                int row = m0 + wm * 64 + mi * 16 + g4 * 4 + i;
                int col = n0 + wn * WN + j * 16 + l15;
                float v = acc[mi][j][i];
                if (OUTF32) ((float*)Cout)[(size_t)row * N + col] = v;
                else        ((u16*)Cout)[(size_t)row * N + col] = f2bf(v);
            }
}

// ---------------- pipelined GEMM (R9): BM=128 BK=64, for WO ----------------
// XCD-cluster mapping: XCD j owns 16m x 2n.
template <int BN, int OUTF32>
__global__ __launch_bounds__(512) void gemm4p(const u16* __restrict__ A, const u16* __restrict__ Bt,
                                              void* __restrict__ Cout, int M, int N, int K) {
    constexpr int NF = BN / 64;
    constexpr int LB = BN / 128;
    constexpr int DBUF = (128 + BN) * 64;
    constexpr int BHALF = (BN / 2) * 64;
    __shared__ __attribute__((aligned(16))) u16 lds[2 * DBUF];

    int bid = blockIdx.x;
    int m0 = ((bid >> 3) & 15) * 128;
    int n0 = ((bid & 7) * 2 + (bid >> 7)) * BN;
    int tid = threadIdx.x, lane = tid & 63, wid = tid >> 6;
    int wm = wid >> 2, wn = wid & 3;
    int l15 = lane & 15, g4 = lane >> 4;
    int sw = l15 & 7;
    int srow = tid >> 3;
    int sslot8 = (((tid & 7) ^ ((tid >> 3) & 7))) * 8;
    int brow0 = (wn & 1) * (BN / 4);
    int NK = K / 64;

    auto STAGE_A = [&](int kt, int h) {
        gload16(&A[(size_t)(m0 + h * 64 + srow) * K + kt * 64 + sslot8],
                &lds[(kt & 1) * DBUF + h * 4096 + wid * 512]);
    };
    auto STAGE_B = [&](int kt, int bh) {
#pragma unroll
        for (int it = 0; it < LB; ++it)
            gload16(&Bt[(size_t)(n0 + bh * (BN / 2) + it * 64 + srow) * K + kt * 64 + sslot8],
                    &lds[(kt & 1) * DBUF + 8192 + bh * BHALF + it * 4096 + wid * 512]);
    };

    f32x4 acc[4][NF];
#pragma unroll
    for (int i = 0; i < 4; ++i)
#pragma unroll
        for (int j = 0; j < NF; ++j) acc[i][j] = (f32x4){0.f, 0.f, 0.f, 0.f};

    STAGE_A(0, 0); STAGE_A(0, 1); STAGE_B(0, 0); STAGE_B(0, 1);
    STAGE_A(1, 0); STAGE_A(1, 1); STAGE_B(1, 0); STAGE_B(1, 1);
    VMC(2 + 2 * LB);
    BAR(); SCHB();

    for (int g = 0; g < NK; ++g) {
        const u16* dd = &lds[(g & 1) * DBUF];
        const u16* aw = dd + wm * 4096;
        const u16* bw = dd + 8192 + (wn >> 1) * BHALF;
        bool mid = (g > 0) && (g + 1 < NK);
        bf16x8 bfr[NF], af0, af1;

#pragma unroll
        for (int nf = 0; nf < NF; ++nf)
            bfr[nf] = *(const bf16x8*)&bw[(brow0 + nf * 16 + l15) * 64 + ((g4 ^ sw) * 8)];
        af0 = *(const bf16x8*)&aw[(0 * 16 + l15) * 64 + ((g4 ^ sw) * 8)];
        af1 = *(const bf16x8*)&aw[(1 * 16 + l15) * 64 + ((g4 ^ sw) * 8)];
        if (mid) STAGE_A(g + 1, 0);
        BAR(); LGKM0();
        __builtin_amdgcn_s_setprio(1);
#pragma unroll
        for (int nf = 0; nf < NF; ++nf) {
            acc[0][nf] = __builtin_amdgcn_mfma_f32_16x16x32_bf16(af0, bfr[nf], acc[0][nf], 0, 0, 0);
            acc[1][nf] = __builtin_amdgcn_mfma_f32_16x16x32_bf16(af1, bfr[nf], acc[1][nf], 0, 0, 0);
        }
        __builtin_amdgcn_s_setprio(0);
        BAR();

        af0 = *(const bf16x8*)&aw[(2 * 16 + l15) * 64 + ((g4 ^ sw) * 8)];
        af1 = *(const bf16x8*)&aw[(3 * 16 + l15) * 64 + ((g4 ^ sw) * 8)];
        if (mid) STAGE_B(g + 1, 1);
        BAR(); LGKM0();
        __builtin_amdgcn_s_setprio(1);
#pragma unroll
        for (int nf = 0; nf < NF; ++nf) {
            acc[2][nf] = __builtin_amdgcn_mfma_f32_16x16x32_bf16(af0, bfr[nf], acc[2][nf], 0, 0, 0);
            acc[3][nf] = __builtin_amdgcn_mfma_f32_16x16x32_bf16(af1, bfr[nf], acc[3][nf], 0, 0, 0);
        }
        __builtin_amdgcn_s_setprio(0);
        BAR();

#pragma unroll
        for (int nf = 0; nf < NF; ++nf)
            bfr[nf] = *(const bf16x8*)&bw[(brow0 + nf * 16 + l15) * 64 + (((4 + g4) ^ sw) * 8)];
        af0 = *(const bf16x8*)&aw[(0 * 16 + l15) * 64 + (((4 + g4) ^ sw) * 8)];
        af1 = *(const bf16x8*)&aw[(1 * 16 + l15) * 64 + (((4 + g4) ^ sw) * 8)];
        if (mid) STAGE_A(g + 1, 1);
        BAR(); LGKM0();
        __builtin_amdgcn_s_setprio(1);
#pragma unroll
        for (int nf = 0; nf < NF; ++nf) {
            acc[0][nf] = __builtin_amdgcn_mfma_f32_16x16x32_bf16(af0, bfr[nf], acc[0][nf], 0, 0, 0);
            acc[1][nf] = __builtin_amdgcn_mfma_f32_16x16x32_bf16(af1, bfr[nf], acc[1][nf], 0, 0, 0);
        }
        __builtin_amdgcn_s_setprio(0);
        BAR();

        af0 = *(const bf16x8*)&aw[(2 * 16 + l15) * 64 + (((4 + g4) ^ sw) * 8)];
        af1 = *(const bf16x8*)&aw[(3 * 16 + l15) * 64 + (((4 + g4) ^ sw) * 8)];
        if (g + 2 < NK) STAGE_B(g + 2, 0);
        BAR(); LGKM0();
        __builtin_amdgcn_s_setprio(1);
#pragma unroll
        for (int nf = 0; nf < NF; ++nf) {
            acc[2][nf] = __builtin_amdgcn_mfma_f32_16x16x32_bf16(af0, bfr[nf], acc[2][nf], 0, 0, 0);
            acc[3][nf] = __builtin_amdgcn_mfma_f32_16x16x32_bf16(af1, bfr[nf], acc[3][nf], 0, 0, 0);
        }
        __builtin_amdgcn_s_setprio(0);
        if (g <= NK - 3)      VMC(LB);
        else if (g == NK - 2) VMC(0);
        BAR(); SCHB();
    }

#pragma unroll
    for (int mf = 0; mf < 4; ++mf)
#pragma unroll
        for (int nf = 0; nf < NF; ++nf)
#pragma unroll
            for (int i = 0; i < 4; ++i) {
                int row = m0 + wm * 64 + mf * 16 + g4 * 4 + i;
                int col = n0 + wn * (BN / 4) + nf * 16 + l15;
                float v = acc[mf][nf][i];
                if (OUTF32) ((float*)Cout)[(size_t)row * N + col] = v;
                else        ((u16*)Cout)[(size_t)row * N + col] = f2bf(v);
            }
}

// ------ RoPE in-place on q,k slices (bf16), LDS trig table; Q pre-scaled by 1/sqrt(d) ------
__global__ __launch_bounds__(256) void ropek(u16* __restrict__ qkvb, const int* __restrict__ positions) {
    __shared__ float cs_[64], sn_[64];
    int t = blockIdx.x;
    float pos = (float)positions[t];
    if (threadIdx.x < 64) {
        int d = threadIdx.x;
        float inv = exp2f(-(float)d * (19.931568569324174f / 64.0f));
        float fr = pos * inv;
        cs_[d] = cosf(fr);
        sn_[d] = sinf(fr);
    }
    __syncthreads();
#pragma unroll
    for (int it = 0; it < 10; ++it) {
        int ci = it * 256 + threadIdx.x;
        int hh = ci >> 6, d = ci & 63;
        int base = (hh < NH) ? hh * HD : KOFF + (hh - NH) * HD;
        size_t off = (size_t)t * QKVN + base + d;
        float x1 = bf2f(qkvb[off]);
        float x2 = bf2f(qkvb[off + 64]);
        float s = sn_[d], c = cs_[d];
        float y1 = x1 * c - x2 * s;
        float y2 = x2 * c + x1 * s;
        if (hh < NH) { y1 *= ATTN_SCALE; y2 *= ATTN_SCALE; }
        qkvb[off]      = f2bf(y1);
        qkvb[off + 64] = f2bf(y2);
    }
}

// ---------------- V^T materialization: qkv v-slice -> vT[NKV][HD][T] ----------------
__global__ __launch_bounds__(256) void vtranspk(const u16* __restrict__ qkvb, u16* __restrict__ vT) {
    __shared__ __attribute__((aligned(16))) u16 tile[64][136];
    int kvh = blockIdx.x, t0 = blockIdx.y * 64;
    int tid = threadIdx.x;
#pragma unroll
    for (int it = 0; it < 4; ++it) {
        int ci = it * 256 + tid;
        int r = ci >> 4, c8 = (ci & 15) * 8;
        *(bf16x8*)&tile[r][c8] = *(const bf16x8*)&qkvb[(size_t)(t0 + r) * QKVN + VOFF + kvh * HD + c8];
    }
    __syncthreads();
#pragma unroll
    for (int it = 0; it < 4; ++it) {
        int ci = it * 256 + tid;
        int d = ci >> 3, tc = (ci & 7) * 8;
        union { bf16x8 v; u16 u[8]; } o;
#pragma unroll
        for (int e = 0; e < 8; ++e) o.u[e] = tile[tc + e][d];
        *(bf16x8*)&vT[((size_t)kvh * HD + d) * T_TOK + t0 + tc] = o.v;
    }
}

// -------- Flash attention: block = (head, 128 q rows), 8 waves x 16 rows --------
// Load-balanced qt mapping: y<8 -> qt=15-y (big tiles), y>=8 -> qt=y-8 (small tiles).
// Co-resident pairs (block i, i+256) then sum to a constant 36 KV-tiles per CU slot pair
// (vs 48/20 with monotone ordering) -> no straggler CUs.
__global__ __launch_bounds__(512) void attnk(const u16* __restrict__ qkvb, const u16* __restrict__ vT,
                                             u16* __restrict__ attnb) {
    __shared__ __attribute__((aligned(16))) u16 kt_[64 * 132];
    __shared__ __attribute__((aligned(16))) u16 vt_[128 * 68];
    __shared__ __attribute__((aligned(16))) u16 pl_[8 * 16 * 68];
    int h = blockIdx.x;
    int y = blockIdx.y;
    int qt = (y < 8) ? (15 - y) : (y - 8);
    int kvh = h >> 2;
    int q0 = qt * 128;
    int tid = threadIdx.x, lane = tid & 63, wid = tid >> 6;
    int l15 = lane & 15, g = lane >> 4;

    const u16* kbase = qkvb + KOFF + (size_t)kvh * HD;
    const u16* vbase = vT + (size_t)kvh * HD * T_TOK;

    bf16x8 qf[4];
    int qrow = q0 + wid * 16 + l15;
#pragma unroll
    for (int ks = 0; ks < 4; ++ks)
        qf[ks] = *(const bf16x8*)&qkvb[(size_t)qrow * QKVN + h * HD + ks * 32 + g * 8];

    f32x4 o[8];
#pragma unroll
    for (int df = 0; df < 8; ++df) o[df] = (f32x4){0.f, 0.f, 0.f, 0.f};
    float m_run[4], l_run[4];
#pragma unroll
    for (int i = 0; i < 4; ++i) { m_run[i] = -3.0e38f; l_run[i] = 0.f; }

    int NT = 2 * qt + 2;

    bf16x8 kreg[2], vreg[2];
#pragma unroll
    for (int it = 0; it < 2; ++it) {
        int gi = it * 512 + tid;
        kreg[it] = *(const bf16x8*)&kbase[(size_t)(gi >> 4) * QKVN + (gi & 15) * 8];
        vreg[it] = *(const bf16x8*)&vbase[(size_t)(gi >> 3) * T_TOK + (gi & 7) * 8];
    }
#pragma unroll
    for (int it = 0; it < 2; ++it) {
        int gi = it * 512 + tid;
        *(bf16x8*)&kt_[(gi >> 4) * 132 + (gi & 15) * 8] = kreg[it];
        *(bf16x8*)&vt_[(gi >> 3) * 68 + (gi & 7) * 8] = vreg[it];
    }
#pragma unroll
    for (int it = 0; it < 2; ++it) {
        int gi = it * 512 + tid;
        kreg[it] = *(const bf16x8*)&kbase[(size_t)(64 + (gi >> 4)) * QKVN + (gi & 15) * 8];
        vreg[it] = *(const bf16x8*)&vbase[(size_t)(gi >> 3) * T_TOK + 64 + (gi & 7) * 8];
    }
    __syncthreads();

    for (int kt2 = 0; kt2 < NT; ++kt2) {
        int kvb = kt2 * 64;
        bool active = (kvb <= q0 + wid * 16 + 15);
        bool diag   = (kvb + 63 > q0 + wid * 16);

        if (active) {
            f32x4 s[4];
#pragma unroll
            for (int nf = 0; nf < 4; ++nf) s[nf] = (f32x4){0.f, 0.f, 0.f, 0.f};
            __builtin_amdgcn_s_setprio(1);
#pragma unroll
            for (int ks = 0; ks < 4; ++ks) {
#pragma unroll
                for (int nf = 0; nf < 4; ++nf) {
                    bf16x8 bfr = *(const bf16x8*)&kt_[(nf * 16 + l15) * 132 + ks * 32 + g * 8];
                    s[nf] = __builtin_amdgcn_mfma_f32_16x16x32_bf16(qf[ks], bfr, s[nf], 0, 0, 0);
                }
            }
            __builtin_amdgcn_s_setprio(0);

            float mloc[4];
#pragma unroll
            for (int i = 0; i < 4; ++i) {
                int qr = q0 + wid * 16 + g * 4 + i;
                float mx = -3.0e38f;
#pragma unroll
                for (int nf = 0; nf < 4; ++nf) {
                    float v = s[nf][i];
                    if (diag) {
                        int kvc = kvb + nf * 16 + l15;
                        v = (kvc <= qr) ? v : -1.0e30f;
                        s[nf][i] = v;
                    }
                    mx = fmaxf(mx, v);
                }
                mloc[i] = mx;
            }

            int ok = 1;
#pragma unroll
            for (int i = 0; i < 4; ++i) ok &= (mloc[i] <= m_run[i] + 8.0f) ? 1 : 0;
            if (!__all(ok)) {
                float mrow[4];
#pragma unroll
                for (int i = 0; i < 4; ++i) mrow[i] = mloc[i];
#pragma unroll
                for (int dd = 1; dd < 16; dd <<= 1)
#pragma unroll
                    for (int i = 0; i < 4; ++i) mrow[i] = fmaxf(mrow[i], __shfl_xor(mrow[i], dd));
                float alpha[4];
#pragma unroll
                for (int i = 0; i < 4; ++i) {
                    float mnew = fmaxf(m_run[i], mrow[i]);
                    alpha[i] = __expf(m_run[i] - mnew);
                    m_run[i] = mnew;
                    l_run[i] *= alpha[i];
                }
#pragma unroll
                for (int df = 0; df < 8; ++df)
#pragma unroll
                    for (int i = 0; i < 4; ++i) o[df][i] *= alpha[i];
            }

#pragma unroll
            for (int nf = 0; nf < 4; ++nf)
#pragma unroll
                for (int i = 0; i < 4; ++i) {
                    float p = __expf(s[nf][i] - m_run[i]);
                    l_run[i] += p;
                    pl_[wid * 1088 + (g * 4 + i) * 68 + nf * 16 + l15] = f2bf(p);
                }

            __builtin_amdgcn_s_setprio(1);
#pragma unroll
            for (int ks2 = 0; ks2 < 2; ++ks2) {
                bf16x8 af = *(const bf16x8*)&pl_[wid * 1088 + l15 * 68 + ks2 * 32 + g * 8];
#pragma unroll
                for (int df = 0; df < 8; ++df) {
                    bf16x8 bfr = *(const bf16x8*)&vt_[(df * 16 + l15) * 68 + ks2 * 32 + g * 8];
                    o[df] = __builtin_amdgcn_mfma_f32_16x16x32_bf16(af, bfr, o[df], 0, 0, 0);
                }
            }
            __builtin_amdgcn_s_setprio(0);
        }

        if (kt2 < NT - 1) {
            __syncthreads();
#pragma unroll
            for (int it = 0; it < 2; ++it) {
                int gi = it * 512 + tid;
                *(bf16x8*)&kt_[(gi >> 4) * 132 + (gi & 15) * 8] = kreg[it];
                *(bf16x8*)&vt_[(gi >> 3) * 68 + (gi & 7) * 8] = vreg[it];
            }
            int ktl = (kt2 + 2 < NT) ? kt2 + 2 : NT - 1;
#pragma unroll
            for (int it = 0; it < 2; ++it) {
                int gi = it * 512 + tid;
                kreg[it] = *(const bf16x8*)&kbase[(size_t)(ktl * 64 + (gi >> 4)) * QKVN + (gi & 15) * 8];
                vreg[it] = *(const bf16x8*)&vbase[(size_t)(gi >> 3) * T_TOK + ktl * 64 + (gi & 7) * 8];
            }
            __syncthreads();
        }
    }

#pragma unroll
    for (int dd = 1; dd < 16; dd <<= 1)
#pragma unroll
        for (int i = 0; i < 4; ++i) l_run[i] += __shfl_xor(l_run[i], dd);

#pragma unroll
    for (int df = 0; df < 8; ++df)
#pragma unroll
        for (int i = 0; i < 4; ++i) {
            int qr = q0 + wid * 16 + g * 4 + i;
            int col = h * HD + df * 16 + l15;
            attnb[(size_t)qr * (NH * HD) + col] = f2bf(o[df][i] / l_run[i]);
        }
}

extern "C" void kernel_launch(void* const* d_in, const int* in_sizes, int n_in,
                              void* d_out, int out_size, void* d_ws, size_t ws_size,
                              hipStream_t stream) {
    const int*   positions = (const int*)d_in[0];
    const float* hs        = (const float*)d_in[1];
    const float* wqkv      = (const float*)d_in[2];
    const float* wo        = (const float*)d_in[3];
    float* out = (float*)d_out;

    char* ws = (char*)d_ws;
    u16* hsb   = (u16*)(ws);                                   // 16,777,216  (reused as attnb)
    u16* wqkvT = (u16*)(ws + 16777216);                        // 50,331,648
    u16* woT   = (u16*)(ws + 16777216 + 50331648);             // 33,554,432
    u16* qkvb  = (u16*)(ws + 16777216 + 50331648 + 33554432);  // 25,165,824
    u16* vT    = (u16*)(ws + 16777216 + 50331648 + 33554432 + 25165824); // 4,194,304
    u16* attnb = hsb;

    convk<<<8192, 256, 0, stream>>>(hs, hsb);
    transpk<<<dim3(96, 64), 256, 0, stream>>>(wqkv, wqkvT, HID, QKVN);
    transpk<<<dim3(64, 64), 256, 0, stream>>>(wo, woT, HID, HID);

    // QKV GEMM: 256x192 tiles, XCD-cluster mapping (8m x 4n per XCD), 256 blocks
    gemm8p<192, 0><<<dim3(256), 512, 0, stream>>>(hsb, wqkvT, qkvb, T_TOK, QKVN, HID);

    ropek<<<T_TOK, 256, 0, stream>>>(qkvb, positions);

    vtranspk<<<dim3(NKV, 32), 256, 0, stream>>>(qkvb, vT);

    // attention: 128-row q tiles, 8 waves x 16 rows, 512 blocks, balanced qt pairing
    attnk<<<dim3(NH, 16), 512, 0, stream>>>(qkvb, vT, attnb);

    // WO GEMM: BM=128 BN=256, XCD-cluster mapping (16m x 2n per XCD), 256 blocks
    gemm4p<256, 1><<<dim3(256), 512, 0, stream>>>(attnb, woT, out, T_TOK, HID, HID);
}

// Round 17
// 315.629 us; speedup vs baseline: 1.0530x; 1.0530x over previous
//
#include <hip/hip_runtime.h>
#include <hip/hip_bf16.h>

typedef __attribute__((ext_vector_type(8))) short bf16x8;
typedef __attribute__((ext_vector_type(4))) float f32x4;
typedef unsigned short u16;

#define T_TOK 2048
#define HID 4096
#define NH 32
#define NKV 8
#define HD 128
#define QKVN 6144   // (NH + 2*NKV) * HD
#define KOFF 4096   // k column offset in qkv
#define VOFF 5120   // v column offset in qkv
// softmax scale folded with log2(e): Q is pre-scaled so scores are in log2 units
#define QSCALE (0.08838834764831845f * 1.4426950408889634f)
#define THR_LOG2 11.0f   // ~8 nats

static __device__ __forceinline__ float bf2f(u16 x) {
    union { float f; unsigned u; } v; v.u = ((unsigned)x) << 16; return v.f;
}
static __device__ __forceinline__ u16 f2bf(float f) {
    union { float f; unsigned u; } v; v.f = f;
    unsigned u = v.u;
    unsigned r = (u + 0x7fff + ((u >> 16) & 1)) >> 16;
    return (u16)r;
}

// async global->LDS, 16B per lane; LDS dest = WAVE-UNIFORM base (HW adds lane*16B)
static __device__ __forceinline__ void gload16(const u16* g, u16* l) {
    __builtin_amdgcn_global_load_lds((const __attribute__((address_space(1))) void*)g,
                                     (__attribute__((address_space(3))) void*)l, 16, 0, 0);
}

#define VMC(n) asm volatile("s_waitcnt vmcnt(%0)" :: "i"(n) : "memory")
#define LGKM0() asm volatile("s_waitcnt lgkmcnt(0)" ::: "memory")
#define BAR() __builtin_amdgcn_s_barrier()
#define SCHB() __builtin_amdgcn_sched_barrier(0)

// ---------------- elementwise f32 -> bf16 ----------------
__global__ __launch_bounds__(256) void convk(const float* __restrict__ in, u16* __restrict__ out) {
    int i = blockIdx.x * 256 + threadIdx.x;
    float4 v = ((const float4*)in)[i];
    ushort4 o;
    o.x = f2bf(v.x); o.y = f2bf(v.y); o.z = f2bf(v.z); o.w = f2bf(v.w);
    ((ushort4*)out)[i] = o;
}

// ------- merged transpose+convert: wqkv (x<96) and wo (x>=96) in ONE launch -------
__global__ __launch_bounds__(256) void transpk2(const float* __restrict__ wqkv, u16* __restrict__ wqkvT,
                                                const float* __restrict__ wo, u16* __restrict__ woT) {
    __shared__ float tile[64][65];
    int bx = blockIdx.x;
    const float* in; u16* out; int C, c0;
    if (bx < 96) { in = wqkv; out = wqkvT; C = QKVN; c0 = bx * 64; }
    else         { in = wo;   out = woT;   C = HID;  c0 = (bx - 96) * 64; }
    int R = HID;
    int r0 = blockIdx.y * 64;
    int tid = threadIdx.x;
#pragma unroll
    for (int it = 0; it < 4; ++it) {
        int ci = it * 256 + tid;
        int r = ci >> 4, c4 = (ci & 15) * 4;
        float4 v = *(const float4*)&in[(size_t)(r0 + r) * C + c0 + c4];
        tile[r][c4 + 0] = v.x; tile[r][c4 + 1] = v.y; tile[r][c4 + 2] = v.z; tile[r][c4 + 3] = v.w;
    }
    __syncthreads();
#pragma unroll
    for (int it = 0; it < 4; ++it) {
        int ci = it * 256 + tid;
        int c = ci >> 4, rq = (ci & 15) * 4;
        ushort4 o;
        o.x = f2bf(tile[rq + 0][c]); o.y = f2bf(tile[rq + 1][c]);
        o.z = f2bf(tile[rq + 2][c]); o.w = f2bf(tile[rq + 3][c]);
        *(ushort4*)&out[(size_t)(c0 + c) * R + r0 + rq] = o;
    }
}

// ------- pipelined GEMM (R14 best): BM=256 BK=32, depth-3, counted vmcnt, waves 4M x 2N -------
// XCD-cluster mapping: XCD j owns an 8m x 4n cluster (per-K-step miss 176KB).
template <int BN, int OUTF32>
__global__ __launch_bounds__(512) void gemm8p(const u16* __restrict__ A, const u16* __restrict__ Bt,
                                              void* __restrict__ Cout, int M, int N, int K) {
    constexpr int BM = 256, BK = 32;
    constexpr int WN = BN / 2;
    constexpr int NF = WN / 16;
    constexpr int BCH = BN / 16;
    constexpr int CA = 2 + (BCH + 7) / 8;
    constexpr int CB = 2 + BCH / 8;
    constexpr int ABUF = BM * BK;
    constexpr int BBUF = BN * BK;
    constexpr int BUFSZ = ABUF + BBUF;

    __shared__ __attribute__((aligned(16))) u16 lds[4 * BUFSZ];

    int bid = blockIdx.x;
    int m0 = ((bid >> 3) & 7) * BM;
    int n0 = ((bid & 7) * 4 + (bid >> 6)) * BN;
    int tid = threadIdx.x, lane = tid & 63, wid = tid >> 6;
    int wm = wid >> 1, wn = wid & 1;
    int l15 = lane & 15, g4 = lane >> 4;
    int srow = lane >> 2;
    int sslot = (lane & 3) ^ ((lane >> 3) & 3);
    int swz = (g4 ^ ((l15 >> 1) & 3)) * 8;
    int NK = K / BK;
    bool shortw = (CA != CB) && (wid >= 4);

    auto STAGE = [&](int kt, int c) {
        u16* base = &lds[(kt & 3) * BUFSZ];
        size_t kcol = (size_t)kt * BK + sslot * 8;
        if (c < 2) {
            int ch = wid * 2 + c;
            gload16(&A[(size_t)(m0 + ch * 16 + srow) * K + kcol], base + ch * 512);
        } else {
            int ch = (c - 2) * 8 + wid;
            if (ch < BCH)
                gload16(&Bt[(size_t)(n0 + ch * 16 + srow) * K + kcol], base + ABUF + ch * 512);
        }
    };

    f32x4 acc[4][NF];
#pragma unroll
    for (int i = 0; i < 4; ++i)
#pragma unroll
        for (int j = 0; j < NF; ++j) acc[i][j] = (f32x4){0.f, 0.f, 0.f, 0.f};

    for (int t = 0; t < 3; ++t)
        for (int c = 0; c < CA; ++c) STAGE(t, c);
    if (shortw) VMC(2 * CB); else VMC(2 * CA);
    BAR(); SCHB();

    for (int g = 0; g < NK; ++g) {
        const u16* ab = &lds[(g & 3) * BUFSZ];
        const u16* bb = ab + ABUF;

        bf16x8 bfr[NF], af0, af1;
#pragma unroll
        for (int j = 0; j < NF; ++j)
            bfr[j] = *(const bf16x8*)&bb[(wn * WN + j * 16 + l15) * BK + swz];
        af0 = *(const bf16x8*)&ab[(wm * 64 + 0 * 16 + l15) * BK + swz];
        af1 = *(const bf16x8*)&ab[(wm * 64 + 1 * 16 + l15) * BK + swz];
        if (g + 3 < NK) {
            STAGE(g + 3, 0); STAGE(g + 3, 1);
        }
        __builtin_amdgcn_s_setprio(1);
#pragma unroll
        for (int j = 0; j < NF; ++j) {
            acc[0][j] = __builtin_amdgcn_mfma_f32_16x16x32_bf16(af0, bfr[j], acc[0][j], 0, 0, 0);
            acc[1][j] = __builtin_amdgcn_mfma_f32_16x16x32_bf16(af1, bfr[j], acc[1][j], 0, 0, 0);
        }
        __builtin_amdgcn_s_setprio(0);

        bf16x8 af2, af3;
        af2 = *(const bf16x8*)&ab[(wm * 64 + 2 * 16 + l15) * BK + swz];
        af3 = *(const bf16x8*)&ab[(wm * 64 + 3 * 16 + l15) * BK + swz];
        if (g + 3 < NK) {
#pragma unroll
            for (int c = 2; c < CA; ++c) STAGE(g + 3, c);
        }
        __builtin_amdgcn_s_setprio(1);
#pragma unroll
        for (int j = 0; j < NF; ++j) {
            acc[2][j] = __builtin_amdgcn_mfma_f32_16x16x32_bf16(af2, bfr[j], acc[2][j], 0, 0, 0);
            acc[3][j] = __builtin_amdgcn_mfma_f32_16x16x32_bf16(af3, bfr[j], acc[3][j], 0, 0, 0);
        }
        __builtin_amdgcn_s_setprio(0);

        if (g < NK - 3)       { if (shortw) VMC(2 * CB); else VMC(2 * CA); }
        else if (g == NK - 3) { if (shortw) VMC(CB);     else VMC(CA); }
        else if (g == NK - 2) VMC(0);
        BAR(); SCHB();
    }

#pragma unroll
    for (int mi = 0; mi < 4; ++mi)
#pragma unroll
        for (int j = 0; j < NF; ++j)
#pragma unroll
            for (int i = 0; i < 4; ++i) {
                int row = m0 + wm * 64 + mi * 16 + g4 * 4 + i;
                int col = n0 + wn * WN + j * 16 + l15;
                float v = acc[mi][j][i];
                if (OUTF32) ((float*)Cout)[(size_t)row * N + col] = v;
                else        ((u16*)Cout)[(size_t)row * N + col] = f2bf(v);
            }
}

// ---------------- pipelined GEMM (R9): BM=128 BK=64, for WO ----------------
// XCD-cluster mapping: XCD j owns 16m x 2n.
template <int BN, int OUTF32>
__global__ __launch_bounds__(512) void gemm4p(const u16* __restrict__ A, const u16* __restrict__ Bt,
                                              void* __restrict__ Cout, int M, int N, int K) {
    constexpr int NF = BN / 64;
    constexpr int LB = BN / 128;
    constexpr int DBUF = (128 + BN) * 64;
    constexpr int BHALF = (BN / 2) * 64;
    __shared__ __attribute__((aligned(16))) u16 lds[2 * DBUF];

    int bid = blockIdx.x;
    int m0 = ((bid >> 3) & 15) * 128;
    int n0 = ((bid & 7) * 2 + (bid >> 7)) * BN;
    int tid = threadIdx.x, lane = tid & 63, wid = tid >> 6;
    int wm = wid >> 2, wn = wid & 3;
    int l15 = lane & 15, g4 = lane >> 4;
    int sw = l15 & 7;
    int srow = tid >> 3;
    int sslot8 = (((tid & 7) ^ ((tid >> 3) & 7))) * 8;
    int brow0 = (wn & 1) * (BN / 4);
    int NK = K / 64;

    auto STAGE_A = [&](int kt, int h) {
        gload16(&A[(size_t)(m0 + h * 64 + srow) * K + kt * 64 + sslot8],
                &lds[(kt & 1) * DBUF + h * 4096 + wid * 512]);
    };
    auto STAGE_B = [&](int kt, int bh) {
#pragma unroll
        for (int it = 0; it < LB; ++it)
            gload16(&Bt[(size_t)(n0 + bh * (BN / 2) + it * 64 + srow) * K + kt * 64 + sslot8],
                    &lds[(kt & 1) * DBUF + 8192 + bh * BHALF + it * 4096 + wid * 512]);
    };

    f32x4 acc[4][NF];
#pragma unroll
    for (int i = 0; i < 4; ++i)
#pragma unroll
        for (int j = 0; j < NF; ++j) acc[i][j] = (f32x4){0.f, 0.f, 0.f, 0.f};

    STAGE_A(0, 0); STAGE_A(0, 1); STAGE_B(0, 0); STAGE_B(0, 1);
    STAGE_A(1, 0); STAGE_A(1, 1); STAGE_B(1, 0); STAGE_B(1, 1);
    VMC(2 + 2 * LB);
    BAR(); SCHB();

    for (int g = 0; g < NK; ++g) {
        const u16* dd = &lds[(g & 1) * DBUF];
        const u16* aw = dd + wm * 4096;
        const u16* bw = dd + 8192 + (wn >> 1) * BHALF;
        bool mid = (g > 0) && (g + 1 < NK);
        bf16x8 bfr[NF], af0, af1;

#pragma unroll
        for (int nf = 0; nf < NF; ++nf)
            bfr[nf] = *(const bf16x8*)&bw[(brow0 + nf * 16 + l15) * 64 + ((g4 ^ sw) * 8)];
        af0 = *(const bf16x8*)&aw[(0 * 16 + l15) * 64 + ((g4 ^ sw) * 8)];
        af1 = *(const bf16x8*)&aw[(1 * 16 + l15) * 64 + ((g4 ^ sw) * 8)];
        if (mid) STAGE_A(g + 1, 0);
        BAR(); LGKM0();
        __builtin_amdgcn_s_setprio(1);
#pragma unroll
        for (int nf = 0; nf < NF; ++nf) {
            acc[0][nf] = __builtin_amdgcn_mfma_f32_16x16x32_bf16(af0, bfr[nf], acc[0][nf], 0, 0, 0);
            acc[1][nf] = __builtin_amdgcn_mfma_f32_16x16x32_bf16(af1, bfr[nf], acc[1][nf], 0, 0, 0);
        }
        __builtin_amdgcn_s_setprio(0);
        BAR();

        af0 = *(const bf16x8*)&aw[(2 * 16 + l15) * 64 + ((g4 ^ sw) * 8)];
        af1 = *(const bf16x8*)&aw[(3 * 16 + l15) * 64 + ((g4 ^ sw) * 8)];
        if (mid) STAGE_B(g + 1, 1);
        BAR(); LGKM0();
        __builtin_amdgcn_s_setprio(1);
#pragma unroll
        for (int nf = 0; nf < NF; ++nf) {
            acc[2][nf] = __builtin_amdgcn_mfma_f32_16x16x32_bf16(af0, bfr[nf], acc[2][nf], 0, 0, 0);
            acc[3][nf] = __builtin_amdgcn_mfma_f32_16x16x32_bf16(af1, bfr[nf], acc[3][nf], 0, 0, 0);
        }
        __builtin_amdgcn_s_setprio(0);
        BAR();

#pragma unroll
        for (int nf = 0; nf < NF; ++nf)
            bfr[nf] = *(const bf16x8*)&bw[(brow0 + nf * 16 + l15) * 64 + (((4 + g4) ^ sw) * 8)];
        af0 = *(const bf16x8*)&aw[(0 * 16 + l15) * 64 + (((4 + g4) ^ sw) * 8)];
        af1 = *(const bf16x8*)&aw[(1 * 16 + l15) * 64 + (((4 + g4) ^ sw) * 8)];
        if (mid) STAGE_A(g + 1, 1);
        BAR(); LGKM0();
        __builtin_amdgcn_s_setprio(1);
#pragma unroll
        for (int nf = 0; nf < NF; ++nf) {
            acc[0][nf] = __builtin_amdgcn_mfma_f32_16x16x32_bf16(af0, bfr[nf], acc[0][nf], 0, 0, 0);
            acc[1][nf] = __builtin_amdgcn_mfma_f32_16x16x32_bf16(af1, bfr[nf], acc[1][nf], 0, 0, 0);
        }
        __builtin_amdgcn_s_setprio(0);
        BAR();

        af0 = *(const bf16x8*)&aw[(2 * 16 + l15) * 64 + (((4 + g4) ^ sw) * 8)];
        af1 = *(const bf16x8*)&aw[(3 * 16 + l15) * 64 + (((4 + g4) ^ sw) * 8)];
        if (g + 2 < NK) STAGE_B(g + 2, 0);
        BAR(); LGKM0();
        __builtin_amdgcn_s_setprio(1);
#pragma unroll
        for (int nf = 0; nf < NF; ++nf) {
            acc[2][nf] = __builtin_amdgcn_mfma_f32_16x16x32_bf16(af0, bfr[nf], acc[2][nf], 0, 0, 0);
            acc[3][nf] = __builtin_amdgcn_mfma_f32_16x16x32_bf16(af1, bfr[nf], acc[3][nf], 0, 0, 0);
        }
        __builtin_amdgcn_s_setprio(0);
        if (g <= NK - 3)      VMC(LB);
        else if (g == NK - 2) VMC(0);
        BAR(); SCHB();
    }

#pragma unroll
    for (int mf = 0; mf < 4; ++mf)
#pragma unroll
        for (int nf = 0; nf < NF; ++nf)
#pragma unroll
            for (int i = 0; i < 4; ++i) {
                int row = m0 + wm * 64 + mf * 16 + g4 * 4 + i;
                int col = n0 + wn * (BN / 4) + nf * 16 + l15;
                float v = acc[mf][nf][i];
                if (OUTF32) ((float*)Cout)[(size_t)row * N + col] = v;
                else        ((u16*)Cout)[(size_t)row * N + col] = f2bf(v);
            }
}

// ------ RoPE in-place on q,k (bf16), LDS trig table; Q pre-scaled by scale*log2(e) ------
__global__ __launch_bounds__(256) void ropek(u16* __restrict__ qkvb, const int* __restrict__ positions) {
    __shared__ float cs_[64], sn_[64];
    int t = blockIdx.x;
    float pos = (float)positions[t];
    if (threadIdx.x < 64) {
        int d = threadIdx.x;
        float inv = exp2f(-(float)d * (19.931568569324174f / 64.0f));
        float fr = pos * inv;
        cs_[d] = cosf(fr);
        sn_[d] = sinf(fr);
    }
    __syncthreads();
#pragma unroll
    for (int it = 0; it < 10; ++it) {
        int ci = it * 256 + threadIdx.x;
        int hh = ci >> 6, d = ci & 63;
        int base = (hh < NH) ? hh * HD : KOFF + (hh - NH) * HD;
        size_t off = (size_t)t * QKVN + base + d;
        float x1 = bf2f(qkvb[off]);
        float x2 = bf2f(qkvb[off + 64]);
        float s = sn_[d], c = cs_[d];
        float y1 = x1 * c - x2 * s;
        float y2 = x2 * c + x1 * s;
        if (hh < NH) { y1 *= QSCALE; y2 *= QSCALE; }  // scores land in log2 units
        qkvb[off]      = f2bf(y1);
        qkvb[off + 64] = f2bf(y2);
    }
}

// ---------------- V^T materialization: qkv v-slice -> vT[NKV][HD][T] ----------------
__global__ __launch_bounds__(256) void vtranspk(const u16* __restrict__ qkvb, u16* __restrict__ vT) {
    __shared__ __attribute__((aligned(16))) u16 tile[64][136];
    int kvh = blockIdx.x, t0 = blockIdx.y * 64;
    int tid = threadIdx.x;
#pragma unroll
    for (int it = 0; it < 4; ++it) {
        int ci = it * 256 + tid;
        int r = ci >> 4, c8 = (ci & 15) * 8;
        *(bf16x8*)&tile[r][c8] = *(const bf16x8*)&qkvb[(size_t)(t0 + r) * QKVN + VOFF + kvh * HD + c8];
    }
    __syncthreads();
#pragma unroll
    for (int it = 0; it < 4; ++it) {
        int ci = it * 256 + tid;
        int d = ci >> 3, tc = (ci & 7) * 8;
        union { bf16x8 v; u16 u[8]; } o;
#pragma unroll
        for (int e = 0; e < 8; ++e) o.u[e] = tile[tc + e][d];
        *(bf16x8*)&vT[((size_t)kvh * HD + d) * T_TOK + t0 + tc] = o.v;
    }
}

// -------- Flash attention (R14 winner + exp2 softmax): 128 q rows, 8 waves x 16 rows --------
__global__ __launch_bounds__(512) void attnk(const u16* __restrict__ qkvb, const u16* __restrict__ vT,
                                             u16* __restrict__ attnb) {
    __shared__ __attribute__((aligned(16))) u16 kt_[64 * 132];
    __shared__ __attribute__((aligned(16))) u16 vt_[128 * 68];
    __shared__ __attribute__((aligned(16))) u16 pl_[8 * 16 * 68];
    int h = blockIdx.x, qt = 15 - blockIdx.y;   // descending: longest-first greedy dispatch
    int kvh = h >> 2;
    int q0 = qt * 128;
    int tid = threadIdx.x, lane = tid & 63, wid = tid >> 6;
    int l15 = lane & 15, g = lane >> 4;

    const u16* kbase = qkvb + KOFF + (size_t)kvh * HD;
    const u16* vbase = vT + (size_t)kvh * HD * T_TOK;

    bf16x8 qf[4];
    int qrow = q0 + wid * 16 + l15;
#pragma unroll
    for (int ks = 0; ks < 4; ++ks)
        qf[ks] = *(const bf16x8*)&qkvb[(size_t)qrow * QKVN + h * HD + ks * 32 + g * 8];

    f32x4 o[8];
#pragma unroll
    for (int df = 0; df < 8; ++df) o[df] = (f32x4){0.f, 0.f, 0.f, 0.f};
    float m_run[4], l_run[4];   // log2-domain running max; per-lane PARTIAL row sums
#pragma unroll
    for (int i = 0; i < 4; ++i) { m_run[i] = -3.0e38f; l_run[i] = 0.f; }

    int NT = 2 * qt + 2;

    bf16x8 kreg[2], vreg[2];
#pragma unroll
    for (int it = 0; it < 2; ++it) {
        int gi = it * 512 + tid;
        kreg[it] = *(const bf16x8*)&kbase[(size_t)(gi >> 4) * QKVN + (gi & 15) * 8];
        vreg[it] = *(const bf16x8*)&vbase[(size_t)(gi >> 3) * T_TOK + (gi & 7) * 8];
    }
#pragma unroll
    for (int it = 0; it < 2; ++it) {
        int gi = it * 512 + tid;
        *(bf16x8*)&kt_[(gi >> 4) * 132 + (gi & 15) * 8] = kreg[it];
        *(bf16x8*)&vt_[(gi >> 3) * 68 + (gi & 7) * 8] = vreg[it];
    }
#pragma unroll
    for (int it = 0; it < 2; ++it) {
        int gi = it * 512 + tid;
        kreg[it] = *(const bf16x8*)&kbase[(size_t)(64 + (gi >> 4)) * QKVN + (gi & 15) * 8];
        vreg[it] = *(const bf16x8*)&vbase[(size_t)(gi >> 3) * T_TOK + 64 + (gi & 7) * 8];
    }
    __syncthreads();

    for (int kt2 = 0; kt2 < NT; ++kt2) {
        int kvb = kt2 * 64;
        bool active = (kvb <= q0 + wid * 16 + 15);
        bool diag   = (kvb + 63 > q0 + wid * 16);

        if (active) {
            f32x4 s[4];
#pragma unroll
            for (int nf = 0; nf < 4; ++nf) s[nf] = (f32x4){0.f, 0.f, 0.f, 0.f};
            __builtin_amdgcn_s_setprio(1);
#pragma unroll
            for (int ks = 0; ks < 4; ++ks) {
#pragma unroll
                for (int nf = 0; nf < 4; ++nf) {
                    bf16x8 bfr = *(const bf16x8*)&kt_[(nf * 16 + l15) * 132 + ks * 32 + g * 8];
                    s[nf] = __builtin_amdgcn_mfma_f32_16x16x32_bf16(qf[ks], bfr, s[nf], 0, 0, 0);
                }
            }
            __builtin_amdgcn_s_setprio(0);

            float mloc[4];
#pragma unroll
            for (int i = 0; i < 4; ++i) {
                int qr = q0 + wid * 16 + g * 4 + i;
                float mx = -3.0e38f;
#pragma unroll
                for (int nf = 0; nf < 4; ++nf) {
                    float v = s[nf][i];
                    if (diag) {
                        int kvc = kvb + nf * 16 + l15;
                        v = (kvc <= qr) ? v : -1.0e30f;
                        s[nf][i] = v;
                    }
                    mx = fmaxf(mx, v);
                }
                mloc[i] = mx;
            }

            int ok = 1;
#pragma unroll
            for (int i = 0; i < 4; ++i) ok &= (mloc[i] <= m_run[i] + THR_LOG2) ? 1 : 0;
            if (!__all(ok)) {
                float mrow[4];
#pragma unroll
                for (int i = 0; i < 4; ++i) mrow[i] = mloc[i];
#pragma unroll
                for (int dd = 1; dd < 16; dd <<= 1)
#pragma unroll
                    for (int i = 0; i < 4; ++i) mrow[i] = fmaxf(mrow[i], __shfl_xor(mrow[i], dd));
                float alpha[4];
#pragma unroll
                for (int i = 0; i < 4; ++i) {
                    float mnew = fmaxf(m_run[i], mrow[i]);
                    alpha[i] = exp2f(m_run[i] - mnew);
                    m_run[i] = mnew;
                    l_run[i] *= alpha[i];
                }
#pragma unroll
                for (int df = 0; df < 8; ++df)
#pragma unroll
                    for (int i = 0; i < 4; ++i) o[df][i] *= alpha[i];
            }

#pragma unroll
            for (int nf = 0; nf < 4; ++nf)
#pragma unroll
                for (int i = 0; i < 4; ++i) {
                    float p = exp2f(s[nf][i] - m_run[i]);
                    l_run[i] += p;
                    pl_[wid * 1088 + (g * 4 + i) * 68 + nf * 16 + l15] = f2bf(p);
                }

            __builtin_amdgcn_s_setprio(1);
#pragma unroll
            for (int ks2 = 0; ks2 < 2; ++ks2) {
                bf16x8 af = *(const bf16x8*)&pl_[wid * 1088 + l15 * 68 + ks2 * 32 + g * 8];
#pragma unroll
                for (int df = 0; df < 8; ++df) {
                    bf16x8 bfr = *(const bf16x8*)&vt_[(df * 16 + l15) * 68 + ks2 * 32 + g * 8];
                    o[df] = __builtin_amdgcn_mfma_f32_16x16x32_bf16(af, bfr, o[df], 0, 0, 0);
                }
            }
            __builtin_amdgcn_s_setprio(0);
        }

        if (kt2 < NT - 1) {
            __syncthreads();
#pragma unroll
            for (int it = 0; it < 2; ++it) {
                int gi = it * 512 + tid;
                *(bf16x8*)&kt_[(gi >> 4) * 132 + (gi & 15) * 8] = kreg[it];
                *(bf16x8*)&vt_[(gi >> 3) * 68 + (gi & 7) * 8] = vreg[it];
            }
            int ktl = (kt2 + 2 < NT) ? kt2 + 2 : NT - 1;
#pragma unroll
            for (int it = 0; it < 2; ++it) {
                int gi = it * 512 + tid;
                kreg[it] = *(const bf16x8*)&kbase[(size_t)(ktl * 64 + (gi >> 4)) * QKVN + (gi & 15) * 8];
                vreg[it] = *(const bf16x8*)&vbase[(size_t)(gi >> 3) * T_TOK + ktl * 64 + (gi & 7) * 8];
            }
            __syncthreads();
        }
    }

#pragma unroll
    for (int dd = 1; dd < 16; dd <<= 1)
#pragma unroll
        for (int i = 0; i < 4; ++i) l_run[i] += __shfl_xor(l_run[i], dd);

#pragma unroll
    for (int df = 0; df < 8; ++df)
#pragma unroll
        for (int i = 0; i < 4; ++i) {
            int qr = q0 + wid * 16 + g * 4 + i;
            int col = h * HD + df * 16 + l15;
            attnb[(size_t)qr * (NH * HD) + col] = f2bf(o[df][i] / l_run[i]);
        }
}

extern "C" void kernel_launch(void* const* d_in, const int* in_sizes, int n_in,
                              void* d_out, int out_size, void* d_ws, size_t ws_size,
                              hipStream_t stream) {
    const int*   positions = (const int*)d_in[0];
    const float* hs        = (const float*)d_in[1];
    const float* wqkv      = (const float*)d_in[2];
    const float* wo        = (const float*)d_in[3];
    float* out = (float*)d_out;

    char* ws = (char*)d_ws;
    u16* hsb   = (u16*)(ws);                                   // 16,777,216  (reused as attnb)
    u16* wqkvT = (u16*)(ws + 16777216);                        // 50,331,648
    u16* woT   = (u16*)(ws + 16777216 + 50331648);             // 33,554,432
    u16* qkvb  = (u16*)(ws + 16777216 + 50331648 + 33554432);  // 25,165,824
    u16* vT    = (u16*)(ws + 16777216 + 50331648 + 33554432 + 25165824); // 4,194,304
    u16* attnb = hsb;

    convk<<<8192, 256, 0, stream>>>(hs, hsb);
    transpk2<<<dim3(160, 64), 256, 0, stream>>>(wqkv, wqkvT, wo, woT);

    // QKV GEMM: 256x192 tiles, XCD-cluster mapping (8m x 4n per XCD), 256 blocks
    gemm8p<192, 0><<<dim3(256), 512, 0, stream>>>(hsb, wqkvT, qkvb, T_TOK, QKVN, HID);

    ropek<<<T_TOK, 256, 0, stream>>>(qkvb, positions);

    vtranspk<<<dim3(NKV, 32), 256, 0, stream>>>(qkvb, vT);

    // attention: 128-row q tiles, 8 waves x 16 rows, 512 blocks, descending qt
    attnk<<<dim3(NH, 16), 512, 0, stream>>>(qkvb, vT, attnb);

    // WO GEMM: BM=128 BN=256, XCD-cluster mapping (16m x 2n per XCD), 256 blocks
    gemm4p<256, 1><<<dim3(256), 512, 0, stream>>>(attnb, woT, out, T_TOK, HID, HID);
}

// Round 18
// 312.255 us; speedup vs baseline: 1.0644x; 1.0108x over previous
//
#include <hip/hip_runtime.h>
#include <hip/hip_bf16.h>

typedef __attribute__((ext_vector_type(8))) short bf16x8;
typedef __attribute__((ext_vector_type(4))) float f32x4;
typedef unsigned short u16;

#define T_TOK 2048
#define HID 4096
#define NH 32
#define NKV 8
#define HD 128
#define QKVN 6144   // (NH + 2*NKV) * HD
#define KOFF 4096   // k column offset in qkv
#define VOFF 5120   // v column offset in qkv
// softmax scale folded with log2(e): Q is pre-scaled so scores are in log2 units
#define QSCALE (0.08838834764831845f * 1.4426950408889634f)
#define THR_LOG2 11.0f   // ~8 nats

static __device__ __forceinline__ float bf2f(u16 x) {
    union { float f; unsigned u; } v; v.u = ((unsigned)x) << 16; return v.f;
}
static __device__ __forceinline__ u16 f2bf(float f) {
    union { float f; unsigned u; } v; v.f = f;
    unsigned u = v.u;
    unsigned r = (u + 0x7fff + ((u >> 16) & 1)) >> 16;
    return (u16)r;
}

// async global->LDS, 16B per lane; LDS dest = WAVE-UNIFORM base (HW adds lane*16B)
static __device__ __forceinline__ void gload16(const u16* g, u16* l) {
    __builtin_amdgcn_global_load_lds((const __attribute__((address_space(1))) void*)g,
                                     (__attribute__((address_space(3))) void*)l, 16, 0, 0);
}

#define VMC(n) asm volatile("s_waitcnt vmcnt(%0)" :: "i"(n) : "memory")
#define LGKM0() asm volatile("s_waitcnt lgkmcnt(0)" ::: "memory")
#define BAR() __builtin_amdgcn_s_barrier()
#define SCHB() __builtin_amdgcn_sched_barrier(0)

// ------- merged prep: weight transposes (y<64) + hs f32->bf16 conv (y>=64) -------
__global__ __launch_bounds__(256) void prepk(const float* __restrict__ hs, u16* __restrict__ hsb,
                                             const float* __restrict__ wqkv, u16* __restrict__ wqkvT,
                                             const float* __restrict__ wo, u16* __restrict__ woT) {
    __shared__ float tile[64][65];
    int by = blockIdx.y;
    int tid = threadIdx.x;
    if (by >= 64) {
        // conv: 160 x 8 = 1280 blocks, grid-stride over 2048*4096/4 float4 elements
        int b = blockIdx.x + 160 * (by - 64);
        for (int i = b * 256 + tid; i < (T_TOK * HID / 4); i += 1280 * 256) {
            float4 v = ((const float4*)hs)[i];
            ushort4 o;
            o.x = f2bf(v.x); o.y = f2bf(v.y); o.z = f2bf(v.z); o.w = f2bf(v.w);
            ((ushort4*)hsb)[i] = o;
        }
        return;
    }
    int bx = blockIdx.x;
    const float* in; u16* out; int C, c0;
    if (bx < 96) { in = wqkv; out = wqkvT; C = QKVN; c0 = bx * 64; }
    else         { in = wo;   out = woT;   C = HID;  c0 = (bx - 96) * 64; }
    int R = HID;
    int r0 = by * 64;
#pragma unroll
    for (int it = 0; it < 4; ++it) {
        int ci = it * 256 + tid;
        int r = ci >> 4, c4 = (ci & 15) * 4;
        float4 v = *(const float4*)&in[(size_t)(r0 + r) * C + c0 + c4];
        tile[r][c4 + 0] = v.x; tile[r][c4 + 1] = v.y; tile[r][c4 + 2] = v.z; tile[r][c4 + 3] = v.w;
    }
    __syncthreads();
#pragma unroll
    for (int it = 0; it < 4; ++it) {
        int ci = it * 256 + tid;
        int c = ci >> 4, rq = (ci & 15) * 4;
        ushort4 o;
        o.x = f2bf(tile[rq + 0][c]); o.y = f2bf(tile[rq + 1][c]);
        o.z = f2bf(tile[rq + 2][c]); o.w = f2bf(tile[rq + 3][c]);
        *(ushort4*)&out[(size_t)(c0 + c) * R + r0 + rq] = o;
    }
}

// ------- pipelined GEMM (R14 best): BM=256 BK=32, depth-3, counted vmcnt, waves 4M x 2N -------
// XCD-cluster mapping: XCD j owns an 8m x 4n cluster (per-K-step miss 176KB).
template <int BN, int OUTF32>
__global__ __launch_bounds__(512) void gemm8p(const u16* __restrict__ A, const u16* __restrict__ Bt,
                                              void* __restrict__ Cout, int M, int N, int K) {
    constexpr int BM = 256, BK = 32;
    constexpr int WN = BN / 2;
    constexpr int NF = WN / 16;
    constexpr int BCH = BN / 16;
    constexpr int CA = 2 + (BCH + 7) / 8;
    constexpr int CB = 2 + BCH / 8;
    constexpr int ABUF = BM * BK;
    constexpr int BBUF = BN * BK;
    constexpr int BUFSZ = ABUF + BBUF;

    __shared__ __attribute__((aligned(16))) u16 lds[4 * BUFSZ];

    int bid = blockIdx.x;
    int m0 = ((bid >> 3) & 7) * BM;
    int n0 = ((bid & 7) * 4 + (bid >> 6)) * BN;
    int tid = threadIdx.x, lane = tid & 63, wid = tid >> 6;
    int wm = wid >> 1, wn = wid & 1;
    int l15 = lane & 15, g4 = lane >> 4;
    int srow = lane >> 2;
    int sslot = (lane & 3) ^ ((lane >> 3) & 3);
    int swz = (g4 ^ ((l15 >> 1) & 3)) * 8;
    int NK = K / BK;
    bool shortw = (CA != CB) && (wid >= 4);

    auto STAGE = [&](int kt, int c) {
        u16* base = &lds[(kt & 3) * BUFSZ];
        size_t kcol = (size_t)kt * BK + sslot * 8;
        if (c < 2) {
            int ch = wid * 2 + c;
            gload16(&A[(size_t)(m0 + ch * 16 + srow) * K + kcol], base + ch * 512);
        } else {
            int ch = (c - 2) * 8 + wid;
            if (ch < BCH)
                gload16(&Bt[(size_t)(n0 + ch * 16 + srow) * K + kcol], base + ABUF + ch * 512);
        }
    };

    f32x4 acc[4][NF];
#pragma unroll
    for (int i = 0; i < 4; ++i)
#pragma unroll
        for (int j = 0; j < NF; ++j) acc[i][j] = (f32x4){0.f, 0.f, 0.f, 0.f};

    for (int t = 0; t < 3; ++t)
        for (int c = 0; c < CA; ++c) STAGE(t, c);
    if (shortw) VMC(2 * CB); else VMC(2 * CA);
    BAR(); SCHB();

    for (int g = 0; g < NK; ++g) {
        const u16* ab = &lds[(g & 3) * BUFSZ];
        const u16* bb = ab + ABUF;

        bf16x8 bfr[NF], af0, af1;
#pragma unroll
        for (int j = 0; j < NF; ++j)
            bfr[j] = *(const bf16x8*)&bb[(wn * WN + j * 16 + l15) * BK + swz];
        af0 = *(const bf16x8*)&ab[(wm * 64 + 0 * 16 + l15) * BK + swz];
        af1 = *(const bf16x8*)&ab[(wm * 64 + 1 * 16 + l15) * BK + swz];
        if (g + 3 < NK) {
            STAGE(g + 3, 0); STAGE(g + 3, 1);
        }
        __builtin_amdgcn_s_setprio(1);
#pragma unroll
        for (int j = 0; j < NF; ++j) {
            acc[0][j] = __builtin_amdgcn_mfma_f32_16x16x32_bf16(af0, bfr[j], acc[0][j], 0, 0, 0);
            acc[1][j] = __builtin_amdgcn_mfma_f32_16x16x32_bf16(af1, bfr[j], acc[1][j], 0, 0, 0);
        }
        __builtin_amdgcn_s_setprio(0);

        bf16x8 af2, af3;
        af2 = *(const bf16x8*)&ab[(wm * 64 + 2 * 16 + l15) * BK + swz];
        af3 = *(const bf16x8*)&ab[(wm * 64 + 3 * 16 + l15) * BK + swz];
        if (g + 3 < NK) {
#pragma unroll
            for (int c = 2; c < CA; ++c) STAGE(g + 3, c);
        }
        __builtin_amdgcn_s_setprio(1);
#pragma unroll
        for (int j = 0; j < NF; ++j) {
            acc[2][j] = __builtin_amdgcn_mfma_f32_16x16x32_bf16(af2, bfr[j], acc[2][j], 0, 0, 0);
            acc[3][j] = __builtin_amdgcn_mfma_f32_16x16x32_bf16(af3, bfr[j], acc[3][j], 0, 0, 0);
        }
        __builtin_amdgcn_s_setprio(0);

        if (g < NK - 3)       { if (shortw) VMC(2 * CB); else VMC(2 * CA); }
        else if (g == NK - 3) { if (shortw) VMC(CB);     else VMC(CA); }
        else if (g == NK - 2) VMC(0);
        BAR(); SCHB();
    }

#pragma unroll
    for (int mi = 0; mi < 4; ++mi)
#pragma unroll
        for (int j = 0; j < NF; ++j)
#pragma unroll
            for (int i = 0; i < 4; ++i) {
                int row = m0 + wm * 64 + mi * 16 + g4 * 4 + i;
                int col = n0 + wn * WN + j * 16 + l15;
                float v = acc[mi][j][i];
                if (OUTF32) ((float*)Cout)[(size_t)row * N + col] = v;
                else        ((u16*)Cout)[(size_t)row * N + col] = f2bf(v);
            }
}

// ---------------- pipelined GEMM (R9): BM=128 BK=64, for WO ----------------
// XCD-cluster mapping: XCD j owns 16m x 2n.
template <int BN, int OUTF32>
__global__ __launch_bounds__(512) void gemm4p(const u16* __restrict__ A, const u16* __restrict__ Bt,
                                              void* __restrict__ Cout, int M, int N, int K) {
    constexpr int NF = BN / 64;
    constexpr int LB = BN / 128;
    constexpr int DBUF = (128 + BN) * 64;
    constexpr int BHALF = (BN / 2) * 64;
    __shared__ __attribute__((aligned(16))) u16 lds[2 * DBUF];

    int bid = blockIdx.x;
    int m0 = ((bid >> 3) & 15) * 128;
    int n0 = ((bid & 7) * 2 + (bid >> 7)) * BN;
    int tid = threadIdx.x, lane = tid & 63, wid = tid >> 6;
    int wm = wid >> 2, wn = wid & 3;
    int l15 = lane & 15, g4 = lane >> 4;
    int sw = l15 & 7;
    int srow = tid >> 3;
    int sslot8 = (((tid & 7) ^ ((tid >> 3) & 7))) * 8;
    int brow0 = (wn & 1) * (BN / 4);
    int NK = K / 64;

    auto STAGE_A = [&](int kt, int h) {
        gload16(&A[(size_t)(m0 + h * 64 + srow) * K + kt * 64 + sslot8],
                &lds[(kt & 1) * DBUF + h * 4096 + wid * 512]);
    };
    auto STAGE_B = [&](int kt, int bh) {
#pragma unroll
        for (int it = 0; it < LB; ++it)
            gload16(&Bt[(size_t)(n0 + bh * (BN / 2) + it * 64 + srow) * K + kt * 64 + sslot8],
                    &lds[(kt & 1) * DBUF + 8192 + bh * BHALF + it * 4096 + wid * 512]);
    };

    f32x4 acc[4][NF];
#pragma unroll
    for (int i = 0; i < 4; ++i)
#pragma unroll
        for (int j = 0; j < NF; ++j) acc[i][j] = (f32x4){0.f, 0.f, 0.f, 0.f};

    STAGE_A(0, 0); STAGE_A(0, 1); STAGE_B(0, 0); STAGE_B(0, 1);
    STAGE_A(1, 0); STAGE_A(1, 1); STAGE_B(1, 0); STAGE_B(1, 1);
    VMC(2 + 2 * LB);
    BAR(); SCHB();

    for (int g = 0; g < NK; ++g) {
        const u16* dd = &lds[(g & 1) * DBUF];
        const u16* aw = dd + wm * 4096;
        const u16* bw = dd + 8192 + (wn >> 1) * BHALF;
        bool mid = (g > 0) && (g + 1 < NK);
        bf16x8 bfr[NF], af0, af1;

#pragma unroll
        for (int nf = 0; nf < NF; ++nf)
            bfr[nf] = *(const bf16x8*)&bw[(brow0 + nf * 16 + l15) * 64 + ((g4 ^ sw) * 8)];
        af0 = *(const bf16x8*)&aw[(0 * 16 + l15) * 64 + ((g4 ^ sw) * 8)];
        af1 = *(const bf16x8*)&aw[(1 * 16 + l15) * 64 + ((g4 ^ sw) * 8)];
        if (mid) STAGE_A(g + 1, 0);
        BAR(); LGKM0();
        __builtin_amdgcn_s_setprio(1);
#pragma unroll
        for (int nf = 0; nf < NF; ++nf) {
            acc[0][nf] = __builtin_amdgcn_mfma_f32_16x16x32_bf16(af0, bfr[nf], acc[0][nf], 0, 0, 0);
            acc[1][nf] = __builtin_amdgcn_mfma_f32_16x16x32_bf16(af1, bfr[nf], acc[1][nf], 0, 0, 0);
        }
        __builtin_amdgcn_s_setprio(0);
        BAR();

        af0 = *(const bf16x8*)&aw[(2 * 16 + l15) * 64 + ((g4 ^ sw) * 8)];
        af1 = *(const bf16x8*)&aw[(3 * 16 + l15) * 64 + ((g4 ^ sw) * 8)];
        if (mid) STAGE_B(g + 1, 1);
        BAR(); LGKM0();
        __builtin_amdgcn_s_setprio(1);
#pragma unroll
        for (int nf = 0; nf < NF; ++nf) {
            acc[2][nf] = __builtin_amdgcn_mfma_f32_16x16x32_bf16(af0, bfr[nf], acc[2][nf], 0, 0, 0);
            acc[3][nf] = __builtin_amdgcn_mfma_f32_16x16x32_bf16(af1, bfr[nf], acc[3][nf], 0, 0, 0);
        }
        __builtin_amdgcn_s_setprio(0);
        BAR();

#pragma unroll
        for (int nf = 0; nf < NF; ++nf)
            bfr[nf] = *(const bf16x8*)&bw[(brow0 + nf * 16 + l15) * 64 + (((4 + g4) ^ sw) * 8)];
        af0 = *(const bf16x8*)&aw[(0 * 16 + l15) * 64 + (((4 + g4) ^ sw) * 8)];
        af1 = *(const bf16x8*)&aw[(1 * 16 + l15) * 64 + (((4 + g4) ^ sw) * 8)];
        if (mid) STAGE_A(g + 1, 1);
        BAR(); LGKM0();
        __builtin_amdgcn_s_setprio(1);
#pragma unroll
        for (int nf = 0; nf < NF; ++nf) {
            acc[0][nf] = __builtin_amdgcn_mfma_f32_16x16x32_bf16(af0, bfr[nf], acc[0][nf], 0, 0, 0);
            acc[1][nf] = __builtin_amdgcn_mfma_f32_16x16x32_bf16(af1, bfr[nf], acc[1][nf], 0, 0, 0);
        }
        __builtin_amdgcn_s_setprio(0);
        BAR();

        af0 = *(const bf16x8*)&aw[(2 * 16 + l15) * 64 + (((4 + g4) ^ sw) * 8)];
        af1 = *(const bf16x8*)&aw[(3 * 16 + l15) * 64 + (((4 + g4) ^ sw) * 8)];
        if (g + 2 < NK) STAGE_B(g + 2, 0);
        BAR(); LGKM0();
        __builtin_amdgcn_s_setprio(1);
#pragma unroll
        for (int nf = 0; nf < NF; ++nf) {
            acc[2][nf] = __builtin_amdgcn_mfma_f32_16x16x32_bf16(af0, bfr[nf], acc[2][nf], 0, 0, 0);
            acc[3][nf] = __builtin_amdgcn_mfma_f32_16x16x32_bf16(af1, bfr[nf], acc[3][nf], 0, 0, 0);
        }
        __builtin_amdgcn_s_setprio(0);
        if (g <= NK - 3)      VMC(LB);
        else if (g == NK - 2) VMC(0);
        BAR(); SCHB();
    }

#pragma unroll
    for (int mf = 0; mf < 4; ++mf)
#pragma unroll
        for (int nf = 0; nf < NF; ++nf)
#pragma unroll
            for (int i = 0; i < 4; ++i) {
                int row = m0 + wm * 64 + mf * 16 + g4 * 4 + i;
                int col = n0 + wn * (BN / 4) + nf * 16 + l15;
                float v = acc[mf][nf][i];
                if (OUTF32) ((float*)Cout)[(size_t)row * N + col] = v;
                else        ((u16*)Cout)[(size_t)row * N + col] = f2bf(v);
            }
}

// ------ merged RoPE (x<2048) + V^T materialization (x>=2048) ------
__global__ __launch_bounds__(256) void ropevtk(u16* __restrict__ qkvb, const int* __restrict__ positions,
                                               u16* __restrict__ vT) {
    __shared__ __attribute__((aligned(16))) u16 tile[64][136];
    int bx = blockIdx.x;
    int tid = threadIdx.x;
    if (bx < 2048) {
        __shared__ float cs_[64], sn_[64];
        int t = bx;
        float pos = (float)positions[t];
        if (tid < 64) {
            int d = tid;
            float inv = exp2f(-(float)d * (19.931568569324174f / 64.0f));
            float fr = pos * inv;
            cs_[d] = cosf(fr);
            sn_[d] = sinf(fr);
        }
        __syncthreads();
#pragma unroll
        for (int it = 0; it < 10; ++it) {
            int ci = it * 256 + tid;
            int hh = ci >> 6, d = ci & 63;
            int base = (hh < NH) ? hh * HD : KOFF + (hh - NH) * HD;
            size_t off = (size_t)t * QKVN + base + d;
            float x1 = bf2f(qkvb[off]);
            float x2 = bf2f(qkvb[off + 64]);
            float s = sn_[d], c = cs_[d];
            float y1 = x1 * c - x2 * s;
            float y2 = x2 * c + x1 * s;
            if (hh < NH) { y1 *= QSCALE; y2 *= QSCALE; }  // scores land in log2 units
            qkvb[off]      = f2bf(y1);
            qkvb[off + 64] = f2bf(y2);
        }
        return;
    }
    int idx = bx - 2048;                 // 256 blocks: kvh = idx>>5, t-tile = idx&31
    int kvh = idx >> 5, t0 = (idx & 31) * 64;
#pragma unroll
    for (int it = 0; it < 4; ++it) {
        int ci = it * 256 + tid;
        int r = ci >> 4, c8 = (ci & 15) * 8;
        *(bf16x8*)&tile[r][c8] = *(const bf16x8*)&qkvb[(size_t)(t0 + r) * QKVN + VOFF + kvh * HD + c8];
    }
    __syncthreads();
#pragma unroll
    for (int it = 0; it < 4; ++it) {
        int ci = it * 256 + tid;
        int d = ci >> 3, tc = (ci & 7) * 8;
        union { bf16x8 v; u16 u[8]; } o;
#pragma unroll
        for (int e = 0; e < 8; ++e) o.u[e] = tile[tc + e][d];
        *(bf16x8*)&vT[((size_t)kvh * HD + d) * T_TOK + t0 + tc] = o.v;
    }
}

// -------- Flash attention (R14 winner + exp2 softmax): 128 q rows, 8 waves x 16 rows --------
__global__ __launch_bounds__(512) void attnk(const u16* __restrict__ qkvb, const u16* __restrict__ vT,
                                             u16* __restrict__ attnb) {
    __shared__ __attribute__((aligned(16))) u16 kt_[64 * 132];
    __shared__ __attribute__((aligned(16))) u16 vt_[128 * 68];
    __shared__ __attribute__((aligned(16))) u16 pl_[8 * 16 * 68];
    int h = blockIdx.x, qt = 15 - blockIdx.y;   // descending: longest-first greedy dispatch
    int kvh = h >> 2;
    int q0 = qt * 128;
    int tid = threadIdx.x, lane = tid & 63, wid = tid >> 6;
    int l15 = lane & 15, g = lane >> 4;

    const u16* kbase = qkvb + KOFF + (size_t)kvh * HD;
    const u16* vbase = vT + (size_t)kvh * HD * T_TOK;

    bf16x8 qf[4];
    int qrow = q0 + wid * 16 + l15;
#pragma unroll
    for (int ks = 0; ks < 4; ++ks)
        qf[ks] = *(const bf16x8*)&qkvb[(size_t)qrow * QKVN + h * HD + ks * 32 + g * 8];

    f32x4 o[8];
#pragma unroll
    for (int df = 0; df < 8; ++df) o[df] = (f32x4){0.f, 0.f, 0.f, 0.f};
    float m_run[4], l_run[4];   // log2-domain running max; per-lane PARTIAL row sums
#pragma unroll
    for (int i = 0; i < 4; ++i) { m_run[i] = -3.0e38f; l_run[i] = 0.f; }

    int NT = 2 * qt + 2;

    bf16x8 kreg[2], vreg[2];
#pragma unroll
    for (int it = 0; it < 2; ++it) {
        int gi = it * 512 + tid;
        kreg[it] = *(const bf16x8*)&kbase[(size_t)(gi >> 4) * QKVN + (gi & 15) * 8];
        vreg[it] = *(const bf16x8*)&vbase[(size_t)(gi >> 3) * T_TOK + (gi & 7) * 8];
    }
#pragma unroll
    for (int it = 0; it < 2; ++it) {
        int gi = it * 512 + tid;
        *(bf16x8*)&kt_[(gi >> 4) * 132 + (gi & 15) * 8] = kreg[it];
        *(bf16x8*)&vt_[(gi >> 3) * 68 + (gi & 7) * 8] = vreg[it];
    }
#pragma unroll
    for (int it = 0; it < 2; ++it) {
        int gi = it * 512 + tid;
        kreg[it] = *(const bf16x8*)&kbase[(size_t)(64 + (gi >> 4)) * QKVN + (gi & 15) * 8];
        vreg[it] = *(const bf16x8*)&vbase[(size_t)(gi >> 3) * T_TOK + 64 + (gi & 7) * 8];
    }
    __syncthreads();

    for (int kt2 = 0; kt2 < NT; ++kt2) {
        int kvb = kt2 * 64;
        bool active = (kvb <= q0 + wid * 16 + 15);
        bool diag   = (kvb + 63 > q0 + wid * 16);

        if (active) {
            f32x4 s[4];
#pragma unroll
            for (int nf = 0; nf < 4; ++nf) s[nf] = (f32x4){0.f, 0.f, 0.f, 0.f};
            __builtin_amdgcn_s_setprio(1);
#pragma unroll
            for (int ks = 0; ks < 4; ++ks) {
#pragma unroll
                for (int nf = 0; nf < 4; ++nf) {
                    bf16x8 bfr = *(const bf16x8*)&kt_[(nf * 16 + l15) * 132 + ks * 32 + g * 8];
                    s[nf] = __builtin_amdgcn_mfma_f32_16x16x32_bf16(qf[ks], bfr, s[nf], 0, 0, 0);
                }
            }
            __builtin_amdgcn_s_setprio(0);

            float mloc[4];
#pragma unroll
            for (int i = 0; i < 4; ++i) {
                int qr = q0 + wid * 16 + g * 4 + i;
                float mx = -3.0e38f;
#pragma unroll
                for (int nf = 0; nf < 4; ++nf) {
                    float v = s[nf][i];
                    if (diag) {
                        int kvc = kvb + nf * 16 + l15;
                        v = (kvc <= qr) ? v : -1.0e30f;
                        s[nf][i] = v;
                    }
                    mx = fmaxf(mx, v);
                }
                mloc[i] = mx;
            }

            int ok = 1;
#pragma unroll
            for (int i = 0; i < 4; ++i) ok &= (mloc[i] <= m_run[i] + THR_LOG2) ? 1 : 0;
            if (!__all(ok)) {
                float mrow[4];
#pragma unroll
                for (int i = 0; i < 4; ++i) mrow[i] = mloc[i];
#pragma unroll
                for (int dd = 1; dd < 16; dd <<= 1)
#pragma unroll
                    for (int i = 0; i < 4; ++i) mrow[i] = fmaxf(mrow[i], __shfl_xor(mrow[i], dd));
                float alpha[4];
#pragma unroll
                for (int i = 0; i < 4; ++i) {
                    float mnew = fmaxf(m_run[i], mrow[i]);
                    alpha[i] = exp2f(m_run[i] - mnew);
                    m_run[i] = mnew;
                    l_run[i] *= alpha[i];
                }
#pragma unroll
                for (int df = 0; df < 8; ++df)
#pragma unroll
                    for (int i = 0; i < 4; ++i) o[df][i] *= alpha[i];
            }

#pragma unroll
            for (int nf = 0; nf < 4; ++nf)
#pragma unroll
                for (int i = 0; i < 4; ++i) {
                    float p = exp2f(s[nf][i] - m_run[i]);
                    l_run[i] += p;
                    pl_[wid * 1088 + (g * 4 + i) * 68 + nf * 16 + l15] = f2bf(p);
                }

            __builtin_amdgcn_s_setprio(1);
#pragma unroll
            for (int ks2 = 0; ks2 < 2; ++ks2) {
                bf16x8 af = *(const bf16x8*)&pl_[wid * 1088 + l15 * 68 + ks2 * 32 + g * 8];
#pragma unroll
                for (int df = 0; df < 8; ++df) {
                    bf16x8 bfr = *(const bf16x8*)&vt_[(df * 16 + l15) * 68 + ks2 * 32 + g * 8];
                    o[df] = __builtin_amdgcn_mfma_f32_16x16x32_bf16(af, bfr, o[df], 0, 0, 0);
                }
            }
            __builtin_amdgcn_s_setprio(0);
        }

        if (kt2 < NT - 1) {
            __syncthreads();
#pragma unroll
            for (int it = 0; it < 2; ++it) {
                int gi = it * 512 + tid;
                *(bf16x8*)&kt_[(gi >> 4) * 132 + (gi & 15) * 8] = kreg[it];
                *(bf16x8*)&vt_[(gi >> 3) * 68 + (gi & 7) * 8] = vreg[it];
            }
            int ktl = (kt2 + 2 < NT) ? kt2 + 2 : NT - 1;
#pragma unroll
            for (int it = 0; it < 2; ++it) {
                int gi = it * 512 + tid;
                kreg[it] = *(const bf16x8*)&kbase[(size_t)(ktl * 64 + (gi >> 4)) * QKVN + (gi & 15) * 8];
                vreg[it] = *(const bf16x8*)&vbase[(size_t)(gi >> 3) * T_TOK + ktl * 64 + (gi & 7) * 8];
            }
            __syncthreads();
        }
    }

#pragma unroll
    for (int dd = 1; dd < 16; dd <<= 1)
#pragma unroll
        for (int i = 0; i < 4; ++i) l_run[i] += __shfl_xor(l_run[i], dd);

#pragma unroll
    for (int df = 0; df < 8; ++df)
#pragma unroll
        for (int i = 0; i < 4; ++i) {
            int qr = q0 + wid * 16 + g * 4 + i;
            int col = h * HD + df * 16 + l15;
            attnb[(size_t)qr * (NH * HD) + col] = f2bf(o[df][i] / l_run[i]);
        }
}

extern "C" void kernel_launch(void* const* d_in, const int* in_sizes, int n_in,
                              void* d_out, int out_size, void* d_ws, size_t ws_size,
                              hipStream_t stream) {
    const int*   positions = (const int*)d_in[0];
    const float* hs        = (const float*)d_in[1];
    const float* wqkv      = (const float*)d_in[2];
    const float* wo        = (const float*)d_in[3];
    float* out = (float*)d_out;

    char* ws = (char*)d_ws;
    u16* hsb   = (u16*)(ws);                                   // 16,777,216  (reused as attnb)
    u16* wqkvT = (u16*)(ws + 16777216);                        // 50,331,648
    u16* woT   = (u16*)(ws + 16777216 + 50331648);             // 33,554,432
    u16* qkvb  = (u16*)(ws + 16777216 + 50331648 + 33554432);  // 25,165,824
    u16* vT    = (u16*)(ws + 16777216 + 50331648 + 33554432 + 25165824); // 4,194,304
    u16* attnb = hsb;

    // prep: weight transposes + hs conversion, one launch
    prepk<<<dim3(160, 72), 256, 0, stream>>>(hs, hsb, wqkv, wqkvT, wo, woT);

    // QKV GEMM: 256x192 tiles, XCD-cluster mapping (8m x 4n per XCD), 256 blocks
    gemm8p<192, 0><<<dim3(256), 512, 0, stream>>>(hsb, wqkvT, qkvb, T_TOK, QKVN, HID);

    // RoPE + V^T, one launch
    ropevtk<<<dim3(2048 + 256), 256, 0, stream>>>(qkvb, positions, vT);

    // attention: 128-row q tiles, 8 waves x 16 rows, 512 blocks, descending qt
    attnk<<<dim3(NH, 16), 512, 0, stream>>>(qkvb, vT, attnb);

    // WO GEMM: BM=128 BN=256, XCD-cluster mapping (16m x 2n per XCD), 256 blocks
    gemm4p<256, 1><<<dim3(256), 512, 0, stream>>>(attnb, woT, out, T_TOK, HID, HID);
}